// Round 1
// baseline (110.456 us; speedup 1.0000x reference)
//
#include <hip/hip_runtime.h>
#include <math.h>

#define Bz 2
#define Az 2
#define Cz 10
#define HWz 1024
#define Nz 2048              // HWz * Az
#define ACHW (Az*Cz*HWz)     // 20480
#define NBBOX (Bz*Az*7*HWz)  // 28672
#define NPP   (Bz*Cz*3*HWz)  // 61440
#define EPSf 1e-6f

// ---- passthrough copies: out[40960..] = bbox_preds, out[69632..] = pp_params
__global__ void k_copy(const float* __restrict__ bbox, const float* __restrict__ pp,
                       float* __restrict__ out) {
    int i = blockIdx.x * blockDim.x + threadIdx.x;
    if (i < NBBOX) out[Bz*ACHW + i] = bbox[i];
    if (i < NPP)   out[Bz*ACHW + NBBOX + i] = pp[i];
}

// ---- nearest BEV box per (b,n)
__global__ void k_bev(const float* __restrict__ dec, float4* __restrict__ bev) {
    int i = blockIdx.x * blockDim.x + threadIdx.x;   // b*N + n
    if (i >= Bz*Nz) return;
    const float* d = dec + i*7;
    float x = d[0], y = d[1], dx = d[3], dy = d[4], yaw = d[6];
    const float PI = 3.14159265358979323846f;
    float normed = fabsf(yaw - floorf(yaw/PI + 0.5f) * PI);
    bool swp = normed > PI * 0.25f;
    float w = swp ? dy : dx;
    float h = swp ? dx : dy;
    bev[i] = make_float4(x - 0.5f*w, y - 0.5f*h, x + 0.5f*w, y + 0.5f*h);
}

// ---- per-(b,c) softmax over n; writes PQ[(b*C+c)*N + n] = {p1, q}
__global__ void k_softmax(const float* __restrict__ scores, const float* __restrict__ pp,
                          float2* __restrict__ PQ) {
    int bc = blockIdx.x;
    int b = bc / Cz, c = bc % Cz;
    int tid = threadIdx.x;
    __shared__ float red[256];
    const float* sbase = scores + b*ACHW;
    float vals[Nz/256];
    float mx = -INFINITY;
    #pragma unroll
    for (int j = 0; j < Nz/256; j++) {
        int n = tid + j*256;
        int a = n % Az, hw = n / Az;
        float v = sbase[(a*Cz + c)*HWz + hw];
        vals[j] = v;
        mx = fmaxf(mx, v);
    }
    red[tid] = mx; __syncthreads();
    for (int s = 128; s > 0; s >>= 1) {
        if (tid < s) red[tid] = fmaxf(red[tid], red[tid+s]);
        __syncthreads();
    }
    mx = red[0]; __syncthreads();
    float sum = 0.f;
    #pragma unroll
    for (int j = 0; j < Nz/256; j++) {
        vals[j] = __expf(vals[j] - mx);
        sum += vals[j];
    }
    red[tid] = sum; __syncthreads();
    for (int s = 128; s > 0; s >>= 1) {
        if (tid < s) red[tid] += red[tid+s];
        __syncthreads();
    }
    float inv = 1.f / red[0];
    const float* p1base = pp + b*Cz*3*HWz + (c*3 + 1)*HWz;
    #pragma unroll
    for (int j = 0; j < Nz/256; j++) {
        int n = tid + j*256;
        int hw = n / Az;
        PQ[(b*Cz + c)*Nz + n] = make_float2(p1base[hw], vals[j] * inv);
    }
}

// ---- main: one block per (b,n) row; 256 threads split over m
__global__ __launch_bounds__(256) void k_main(const float4* __restrict__ bev,
                                              const float2* __restrict__ PQ,
                                              const float* __restrict__ pp,
                                              float* __restrict__ out) {
    int row = blockIdx.x;            // b*N + n
    int b = row / Nz, n = row % Nz;
    int tid = threadIdx.x;
    int hw = n / Az;

    float4 bn = bev[row];
    float area_n = (bn.z - bn.x) * (bn.w - bn.y);

    float p0[Cz];
    const float* p0base = pp + b*Cz*3*HWz + hw;
    #pragma unroll
    for (int c = 0; c < Cz; c++) p0[c] = p0base[c*3*HWz];

    float l[Cz], acc[Cz];
    #pragma unroll
    for (int c = 0; c < Cz; c++) { l[c] = 0.f; acc[c] = 0.f; }

    const float4* bevb = bev + b*Nz;
    const float2* pqb  = PQ  + b*Cz*Nz;

    for (int m = tid; m < Nz; m += 256) {
        float4 bm = bevb[m];
        float xx1 = fmaxf(bn.x, bm.x), yy1 = fmaxf(bn.y, bm.y);
        float xx2 = fminf(bn.z, bm.z), yy2 = fminf(bn.w, bm.w);
        float iw = fmaxf(xx2 - xx1, 0.f), ih = fmaxf(yy2 - yy1, 0.f);
        float inter = iw * ih;
        float area_m = (bm.z - bm.x) * (bm.w - bm.y);
        float uni = fmaxf(area_n + area_m - inter, EPSf);
        float iou = inter / uni;
        #pragma unroll
        for (int c = 0; c < Cz; c++) {
            float2 pq = pqb[c*Nz + m];
            float e = __expf(iou + p0[c] * pq.x);
            l[c]   += e;
            acc[c] += e * pq.y;
        }
    }

    // wave-level reduction (64 lanes)
    #pragma unroll
    for (int c = 0; c < Cz; c++) {
        for (int off = 32; off > 0; off >>= 1) {
            l[c]   += __shfl_down(l[c], off);
            acc[c] += __shfl_down(acc[c], off);
        }
    }
    __shared__ float sl[4][Cz], sacc[4][Cz];
    int wave = tid >> 6, lane = tid & 63;
    if (lane == 0) {
        #pragma unroll
        for (int c = 0; c < Cz; c++) { sl[wave][c] = l[c]; sacc[wave][c] = acc[c]; }
    }
    __syncthreads();
    if (tid < Cz) {
        int c = tid;
        float L = sl[0][c] + sl[1][c] + sl[2][c] + sl[3][c];
        float S = sacc[0][c] + sacc[1][c] + sacc[2][c] + sacc[3][c];
        int a = n % Az;
        out[b*ACHW + (a*Cz + c)*HWz + hw] = S / L;
    }
}

extern "C" void kernel_launch(void* const* d_in, const int* in_sizes, int n_in,
                              void* d_out, int out_size, void* d_ws, size_t ws_size,
                              hipStream_t stream) {
    const float* scores = (const float*)d_in[0];
    const float* bbox   = (const float*)d_in[1];
    const float* pp     = (const float*)d_in[2];
    const float* dec    = (const float*)d_in[3];
    float* out = (float*)d_out;

    float4* bev = (float4*)d_ws;
    float2* PQ  = (float2*)((char*)d_ws + (size_t)Bz*Nz*sizeof(float4));

    hipLaunchKernelGGL(k_copy,    dim3((NPP + 255)/256),   dim3(256), 0, stream, bbox, pp, out);
    hipLaunchKernelGGL(k_bev,     dim3((Bz*Nz + 255)/256), dim3(256), 0, stream, dec, bev);
    hipLaunchKernelGGL(k_softmax, dim3(Bz*Cz),             dim3(256), 0, stream, scores, pp, PQ);
    hipLaunchKernelGGL(k_main,    dim3(Bz*Nz),             dim3(256), 0, stream, bev, PQ, pp, out);
}

// Round 2
// 90.578 us; speedup vs baseline: 1.2195x; 1.2195x over previous
//
#include <hip/hip_runtime.h>
#include <math.h>

#define Bz 2
#define Az 2
#define Cz 10
#define HWz 1024
#define Nz 2048              // HWz * Az
#define ACHW (Az*Cz*HWz)     // 20480
#define NBBOX (Bz*Az*7*HWz)  // 28672
#define NPP   (Bz*Cz*3*HWz)  // 61440
#define EPSf 1e-6f
#define LOG2E 1.4426950408889634f

#if __has_builtin(__builtin_amdgcn_exp2f)
#define EXP2F(x) __builtin_amdgcn_exp2f(x)
#else
#define EXP2F(x) exp2f(x)
#endif
#if __has_builtin(__builtin_amdgcn_rcpf)
#define RCPF(x) __builtin_amdgcn_rcpf(x)
#else
#define RCPF(x) (1.0f/(x))
#endif

// ws layout: LT float2[B*N] | RB float2[B*N] | PQ float2[B*C*N]
// PQ[(b*C+c)*N + m] = { p1*log2e, softmax_n(scores)[m,c] }

// ---- fused prep: copy passthroughs + BEV boxes + per-(b,c) softmax
__global__ __launch_bounds__(256) void k_pre(const float* __restrict__ scores,
                                             const float* __restrict__ bbox,
                                             const float* __restrict__ pp,
                                             const float* __restrict__ dec,
                                             float* __restrict__ out,
                                             float2* __restrict__ LT,
                                             float2* __restrict__ RB,
                                             float2* __restrict__ PQ) {
    int blk = blockIdx.x;
    int tid = threadIdx.x;
    __shared__ float red[256];

    if (blk < 240) {                    // ---- passthrough copies
        int i = blk * 256 + tid;
        if (i < NBBOX) out[Bz*ACHW + i] = bbox[i];
        if (i < NPP)   out[Bz*ACHW + NBBOX + i] = pp[i];
        return;
    }
    if (blk < 256) {                    // ---- BEV (4096 boxes)
        int i = (blk - 240) * 256 + tid;
        const float* d = dec + i*7;
        float x = d[0], y = d[1], dx = d[3], dy = d[4], yaw = d[6];
        const float PI = 3.14159265358979323846f;
        float normed = fabsf(yaw - floorf(yaw/PI + 0.5f) * PI);
        bool swp = normed > PI * 0.25f;
        float w = swp ? dy : dx;
        float h = swp ? dx : dy;
        LT[i] = make_float2(x - 0.5f*w, y - 0.5f*h);
        RB[i] = make_float2(x + 0.5f*w, y + 0.5f*h);
        return;
    }
    // ---- softmax over n for (b,c) = blk-256 in [0,20)
    int bc = blk - 256;
    int b = bc / Cz, c = bc % Cz;
    const float* sbase = scores + b*ACHW;
    float vals[Nz/256];
    float mx = -INFINITY;
    #pragma unroll
    for (int j = 0; j < Nz/256; j++) {
        int n = tid + j*256;
        int a = n & 1, hw = n >> 1;
        float v = sbase[(a*Cz + c)*HWz + hw];
        vals[j] = v;
        mx = fmaxf(mx, v);
    }
    red[tid] = mx; __syncthreads();
    for (int s = 128; s > 0; s >>= 1) {
        if (tid < s) red[tid] = fmaxf(red[tid], red[tid+s]);
        __syncthreads();
    }
    mx = red[0]; __syncthreads();
    float sum = 0.f;
    #pragma unroll
    for (int j = 0; j < Nz/256; j++) {
        vals[j] = EXP2F((vals[j] - mx) * LOG2E);
        sum += vals[j];
    }
    red[tid] = sum; __syncthreads();
    for (int s = 128; s > 0; s >>= 1) {
        if (tid < s) red[tid] += red[tid+s];
        __syncthreads();
    }
    float inv = 1.f / red[0];
    const float* p1base = pp + b*Cz*3*HWz + (c*3 + 1)*HWz;
    #pragma unroll
    for (int j = 0; j < Nz/256; j++) {
        int n = tid + j*256;
        int hw = n >> 1;
        PQ[(b*Cz + c)*Nz + n] = make_float2(p1base[hw] * LOG2E, vals[j] * inv);
    }
}

// ---- main: 4 rows per block (one row per wave), m-chunks of 256 staged in LDS
// LDS float2 view: [0..256) = LT chunk, [256..512) = RB chunk,
//                  [512 + c*256 + m] = PQ chunk for channel c
__global__ __launch_bounds__(256, 4) void k_main(const float2* __restrict__ LT,
                                                 const float2* __restrict__ RB,
                                                 const float2* __restrict__ PQ,
                                                 const float* __restrict__ pp,
                                                 float* __restrict__ out) {
    __shared__ float4 S4[1536];          // 24 KB
    float2* Sf2 = (float2*)S4;
    int tid = threadIdx.x;
    int wave = tid >> 6, lane = tid & 63;
    int row = blockIdx.x * 4 + wave;     // b*N + n
    int b = row / Nz, n = row % Nz;
    int hw = n >> 1, a = n & 1;

    float2 ltn = LT[row], rbn = RB[row];
    float area_n = (rbn.x - ltn.x) * (rbn.y - ltn.y);

    float p0[Cz];
    const float* p0base = pp + b*Cz*3*HWz + hw;
    #pragma unroll
    for (int c = 0; c < Cz; c++) p0[c] = p0base[c*3*HWz];

    float l[Cz], acc[Cz];
    #pragma unroll
    for (int c = 0; c < Cz; c++) { l[c] = 0.f; acc[c] = 0.f; }

    const float4* LT4b = (const float4*)(LT + b*Nz);
    const float4* RB4b = (const float4*)(RB + b*Nz);
    const float4* PQ4b = (const float4*)(PQ + b*Cz*Nz);

    for (int chunk = 0; chunk < Nz/256; chunk++) {
        int f40 = chunk * 128;           // float4 base index of this chunk
        __syncthreads();
        #pragma unroll
        for (int k = 0; k < 6; k++) {
            int u = tid + k*256;
            float4 v;
            if (u < 128)       v = LT4b[f40 + u];
            else if (u < 256)  v = RB4b[f40 + (u - 128)];
            else {
                int w2 = u - 256;
                int c = w2 >> 7, i = w2 & 127;
                v = PQ4b[c*(Nz/2) + f40 + i];
            }
            S4[u] = v;
        }
        __syncthreads();
        #pragma unroll
        for (int k2 = 0; k2 < 4; k2++) {
            int m = lane + (k2 << 6);
            float2 bl = Sf2[m];
            float2 br = Sf2[256 + m];
            float xx1 = fmaxf(ltn.x, bl.x), yy1 = fmaxf(ltn.y, bl.y);
            float xx2 = fminf(rbn.x, br.x), yy2 = fminf(rbn.y, br.y);
            float iw = fmaxf(xx2 - xx1, 0.f), ih = fmaxf(yy2 - yy1, 0.f);
            float inter = iw * ih;
            float am = (br.x - bl.x) * (br.y - bl.y);
            float uni = fmaxf(area_n + am - inter, EPSf);
            float iou2 = inter * LOG2E * RCPF(uni);
            #pragma unroll
            for (int c = 0; c < Cz; c++) {
                float2 pq = Sf2[512 + c*256 + m];
                float e = EXP2F(fmaf(p0[c], pq.x, iou2));
                l[c] += e;
                acc[c] = fmaf(e, pq.y, acc[c]);
            }
        }
    }

    // wave reduction (each wave owns one row)
    #pragma unroll
    for (int c = 0; c < Cz; c++) {
        for (int off = 32; off > 0; off >>= 1) {
            l[c]   += __shfl_down(l[c], off);
            acc[c] += __shfl_down(acc[c], off);
        }
    }
    if (lane == 0) {
        #pragma unroll
        for (int c = 0; c < Cz; c++)
            out[b*ACHW + (a*Cz + c)*HWz + hw] = acc[c] / l[c];
    }
}

extern "C" void kernel_launch(void* const* d_in, const int* in_sizes, int n_in,
                              void* d_out, int out_size, void* d_ws, size_t ws_size,
                              hipStream_t stream) {
    const float* scores = (const float*)d_in[0];
    const float* bbox   = (const float*)d_in[1];
    const float* pp     = (const float*)d_in[2];
    const float* dec    = (const float*)d_in[3];
    float* out = (float*)d_out;

    float2* LT = (float2*)d_ws;
    float2* RB = LT + (size_t)Bz*Nz;
    float2* PQ = RB + (size_t)Bz*Nz;

    hipLaunchKernelGGL(k_pre,  dim3(276),  dim3(256), 0, stream,
                       scores, bbox, pp, dec, out, LT, RB, PQ);
    hipLaunchKernelGGL(k_main, dim3(Bz*Nz/4), dim3(256), 0, stream,
                       LT, RB, PQ, pp, out);
}

// Round 3
// 81.411 us; speedup vs baseline: 1.3568x; 1.1126x over previous
//
#include <hip/hip_runtime.h>
#include <math.h>

#define Bz 2
#define Az 2
#define Cz 10
#define HWz 1024
#define Nz 2048              // HWz * Az
#define ACHW (Az*Cz*HWz)     // 20480
#define NBBOX (Bz*Az*7*HWz)  // 28672
#define NPP   (Bz*Cz*3*HWz)  // 61440
#define EPSf 1e-6f
#define LOG2E 1.4426950408889634f

#if __has_builtin(__builtin_amdgcn_exp2f)
#define EXP2F(x) __builtin_amdgcn_exp2f(x)
#else
#define EXP2F(x) exp2f(x)
#endif
#if __has_builtin(__builtin_amdgcn_rcpf)
#define RCPF(x) __builtin_amdgcn_rcpf(x)
#else
#define RCPF(x) (1.0f/(x))
#endif

static __device__ __forceinline__ unsigned short f2bf(float x) {
    unsigned u = __builtin_bit_cast(unsigned, x);
    unsigned r = (u + 0x7fffu + ((u >> 16) & 1u)) >> 16;
    return (unsigned short)r;
}

// wave64 sum via DPP on the VALU pipe (not LDS). Total lands in lane 63.
#if __has_builtin(__builtin_amdgcn_update_dpp)
static __device__ __forceinline__ float wred(float x) {
    int t;
    t = __builtin_amdgcn_update_dpp(0, __builtin_bit_cast(int, x), 0x111, 0xf, 0xf, true);
    x += __builtin_bit_cast(float, t);   // row_shr:1
    t = __builtin_amdgcn_update_dpp(0, __builtin_bit_cast(int, x), 0x112, 0xf, 0xf, true);
    x += __builtin_bit_cast(float, t);   // row_shr:2
    t = __builtin_amdgcn_update_dpp(0, __builtin_bit_cast(int, x), 0x114, 0xf, 0xf, true);
    x += __builtin_bit_cast(float, t);   // row_shr:4
    t = __builtin_amdgcn_update_dpp(0, __builtin_bit_cast(int, x), 0x118, 0xf, 0xf, true);
    x += __builtin_bit_cast(float, t);   // row_shr:8 -> lane15/31/47/63 have row sums
    t = __builtin_amdgcn_update_dpp(0, __builtin_bit_cast(int, x), 0x142, 0xa, 0xf, true);
    x += __builtin_bit_cast(float, t);   // row_bcast:15 into rows 1,3
    t = __builtin_amdgcn_update_dpp(0, __builtin_bit_cast(int, x), 0x143, 0xc, 0xf, true);
    x += __builtin_bit_cast(float, t);   // row_bcast:31 into rows 2,3 -> lane63 total
    return x;
}
#define WRED_LANE 63
#else
static __device__ __forceinline__ float wred(float x) {
    for (int off = 32; off > 0; off >>= 1) x += __shfl_down(x, off);
    return x;
}
#define WRED_LANE 0
#endif

static __device__ __forceinline__ float iou_e(float nx1,float ny1,float nx2,float ny2,float ar,
                                              float mx1,float my1,float mx2,float my2,float am) {
    float xx1 = fmaxf(nx1, mx1), yy1 = fmaxf(ny1, my1);
    float xx2 = fminf(nx2, mx2), yy2 = fminf(ny2, my2);
    float iw = fmaxf(xx2 - xx1, 0.f), ih = fmaxf(yy2 - yy1, 0.f);
    float inter = iw * ih;
    float uni = fmaxf(ar + am - inter, EPSf);
    return EXP2F(inter * LOG2E * RCPF(uni));   // exp2(iou*log2e)
}

// ws: LT float2[B*N] | RB float2[B*N] | GPQ uint2[B][C][HW] = {p1*log2e (f32), bf16(q0)|bf16(q1)<<16}

// ---- fused prep: passthrough copies + BEV + per-(b,c) softmax
__global__ __launch_bounds__(256) void k_pre(const float* __restrict__ scores,
                                             const float* __restrict__ bbox,
                                             const float* __restrict__ pp,
                                             const float* __restrict__ dec,
                                             float* __restrict__ out,
                                             float2* __restrict__ LT,
                                             float2* __restrict__ RB,
                                             uint2* __restrict__ GPQ) {
    int blk = blockIdx.x;
    int tid = threadIdx.x;
    __shared__ float red[256];

    if (blk < 240) {                    // copies
        int i = blk * 256 + tid;
        if (i < NBBOX) out[Bz*ACHW + i] = bbox[i];
        if (i < NPP)   out[Bz*ACHW + NBBOX + i] = pp[i];
        return;
    }
    if (blk < 256) {                    // BEV (4096 boxes)
        int i = (blk - 240) * 256 + tid;
        const float* d = dec + i*7;
        float x = d[0], y = d[1], dx = d[3], dy = d[4], yaw = d[6];
        const float PI = 3.14159265358979323846f;
        float normed = fabsf(yaw - floorf(yaw/PI + 0.5f) * PI);
        bool swp = normed > PI * 0.25f;
        float w = swp ? dy : dx;
        float h = swp ? dx : dy;
        LT[i] = make_float2(x - 0.5f*w, y - 0.5f*h);
        RB[i] = make_float2(x + 0.5f*w, y + 0.5f*h);
        return;
    }
    // softmax over n for (b,c)
    int bc = blk - 256;
    int b = bc / Cz, c = bc % Cz;
    const float* sbase = scores + b*ACHW;
    float vals[Nz/256];
    float mx = -INFINITY;
    #pragma unroll
    for (int j = 0; j < Nz/256; j++) {
        int n = tid + j*256;
        int a = n & 1, hw = n >> 1;
        float v = sbase[(a*Cz + c)*HWz + hw];
        vals[j] = v;
        mx = fmaxf(mx, v);
    }
    red[tid] = mx; __syncthreads();
    for (int s = 128; s > 0; s >>= 1) {
        if (tid < s) red[tid] = fmaxf(red[tid], red[tid+s]);
        __syncthreads();
    }
    mx = red[0]; __syncthreads();
    float sum = 0.f;
    #pragma unroll
    for (int j = 0; j < Nz/256; j++) {
        vals[j] = EXP2F((vals[j] - mx) * LOG2E);
        sum += vals[j];
    }
    red[tid] = sum; __syncthreads();
    for (int s = 128; s > 0; s >>= 1) {
        if (tid < s) red[tid] += red[tid+s];
        __syncthreads();
    }
    float inv = 1.f / red[0];
    const float* p1base = pp + b*Cz*3*HWz + (c*3 + 1)*HWz;
    uint2* gp = GPQ + (b*Cz + c)*HWz;
    #pragma unroll
    for (int j = 0; j < Nz/256; j++) {
        __syncthreads();
        red[tid] = vals[j] * inv;
        __syncthreads();
        if (tid < 128) {
            int hm = (j << 7) + tid;
            float q0 = red[2*tid], q1 = red[2*tid + 1];
            unsigned qq = (unsigned)f2bf(q0) | ((unsigned)f2bf(q1) << 16);
            float p1 = p1base[hm] * LOG2E;
            gp[hm] = make_uint2(__builtin_bit_cast(unsigned, p1), qq);
        }
    }
}

// ---- main: 512 blocks x 256 thr; wave = 1 hw_n (rows n=2hn, 2hn+1); lane = 1 hw_m (m=2hm, 2hm+1)
// chunk = 128 hw_m staged in LDS, register-prefetched
__global__ __launch_bounds__(256) void k_main(const float4* __restrict__ LT4,
                                              const float4* __restrict__ RB4,
                                              const uint2* __restrict__ GPQ,
                                              const float* __restrict__ pp,
                                              float* __restrict__ out) {
    __shared__ float4 SB[256];        // [0..128) LT pairs, [128..256) RB pairs
    __shared__ uint2  SPQ[Cz*128];    // [c][hm]
    int tid = threadIdx.x;
    int wave = tid >> 6, lane = tid & 63;
    int bid = blockIdx.x;
    int b = bid >> 8;
    int hn = ((bid & 255) << 2) + wave;

    const float4* LTb = LT4 + (b << 10);
    const float4* RBb = RB4 + (b << 10);
    const uint2*  PQb = GPQ + b * (Cz * HWz);

    float4 bx = LTb[hn];               // lt of rows 0,1
    float4 by = RBb[hn];               // rb of rows 0,1
    float ar0 = (by.x - bx.x) * (by.y - bx.y);
    float ar1 = (by.z - bx.z) * (by.w - bx.w);

    float p0[Cz];
    const float* p0base = pp + b*(Cz*3*HWz) + hn;
    #pragma unroll
    for (int c = 0; c < Cz; c++) p0[c] = p0base[c * 3 * HWz];

    float l0[Cz], l1[Cz], a0[Cz], a1[Cz];
    #pragma unroll
    for (int c = 0; c < Cz; c++) { l0[c]=0.f; l1[c]=0.f; a0[c]=0.f; a1[c]=0.f; }

    // register prefetch of chunk 0
    float4 rB = (tid < 128) ? LTb[tid] : RBb[tid - 128];
    uint2 rq[5];
    #pragma unroll
    for (int k = 0; k < 5; k++) {
        int u = tid + (k << 8);
        rq[k] = PQb[((u >> 7) << 10) + (u & 127)];
    }

    for (int cb = 0; cb < 8; cb++) {
        __syncthreads();                       // previous chunk fully consumed
        SB[tid] = rB;
        #pragma unroll
        for (int k = 0; k < 5; k++) SPQ[tid + (k << 8)] = rq[k];
        __syncthreads();
        if (cb < 7) {                          // prefetch next chunk during compute
            int nb = (cb + 1) << 7;
            rB = (tid < 128) ? LTb[nb + tid] : RBb[nb + tid - 128];
            #pragma unroll
            for (int k = 0; k < 5; k++) {
                int u = tid + (k << 8);
                rq[k] = PQb[((u >> 7) << 10) + nb + (u & 127)];
            }
        }
        #pragma unroll
        for (int half = 0; half < 2; half++) {
            int hm = (half << 6) + lane;
            float4 bl = SB[hm];
            float4 br = SB[128 + hm];
            float am0 = (br.x - bl.x) * (br.y - bl.y);
            float am1 = (br.z - bl.z) * (br.w - bl.w);
            float E00 = iou_e(bx.x,bx.y,by.x,by.y,ar0, bl.x,bl.y,br.x,br.y,am0);
            float E01 = iou_e(bx.x,bx.y,by.x,by.y,ar0, bl.z,bl.w,br.z,br.w,am1);
            float E10 = iou_e(bx.z,bx.w,by.z,by.w,ar1, bl.x,bl.y,br.x,br.y,am0);
            float E11 = iou_e(bx.z,bx.w,by.z,by.w,ar1, bl.z,bl.w,br.z,br.w,am1);
            float S0 = E00 + E01, S1 = E10 + E11;
            #pragma unroll
            for (int c = 0; c < Cz; c++) {
                uint2 pq = SPQ[(c << 7) + hm];
                float p1 = __builtin_bit_cast(float, pq.x);
                float q0 = __builtin_bit_cast(float, pq.y << 16);
                float q1 = __builtin_bit_cast(float, pq.y & 0xffff0000u);
                float F = EXP2F(p0[c] * p1);
                l0[c] = fmaf(F, S0, l0[c]);
                l1[c] = fmaf(F, S1, l1[c]);
                float t0 = fmaf(E01, q1, E00 * q0);
                float t1 = fmaf(E11, q1, E10 * q0);
                a0[c] = fmaf(F, t0, a0[c]);
                a1[c] = fmaf(F, t1, a1[c]);
            }
        }
    }

    #pragma unroll
    for (int c = 0; c < Cz; c++) {
        l0[c] = wred(l0[c]); l1[c] = wred(l1[c]);
        a0[c] = wred(a0[c]); a1[c] = wred(a1[c]);
    }
    if (lane == WRED_LANE) {
        float* ob = out + b*ACHW + hn;         // n = 2hn+a -> a = row, hw = hn
        #pragma unroll
        for (int c = 0; c < Cz; c++) {
            ob[c * HWz]        = a0[c] * RCPF(l0[c]);
            ob[(Cz + c) * HWz] = a1[c] * RCPF(l1[c]);
        }
    }
}

extern "C" void kernel_launch(void* const* d_in, const int* in_sizes, int n_in,
                              void* d_out, int out_size, void* d_ws, size_t ws_size,
                              hipStream_t stream) {
    const float* scores = (const float*)d_in[0];
    const float* bbox   = (const float*)d_in[1];
    const float* pp     = (const float*)d_in[2];
    const float* dec    = (const float*)d_in[3];
    float* out = (float*)d_out;

    float2* LT = (float2*)d_ws;
    float2* RB = LT + (size_t)Bz*Nz;
    uint2*  PQ = (uint2*)(RB + (size_t)Bz*Nz);

    hipLaunchKernelGGL(k_pre,  dim3(276), dim3(256), 0, stream,
                       scores, bbox, pp, dec, out, LT, RB, PQ);
    hipLaunchKernelGGL(k_main, dim3(512), dim3(256), 0, stream,
                       (const float4*)LT, (const float4*)RB, PQ, pp, out);
}